// Round 8
// baseline (705.973 us; speedup 1.0000x reference)
//
#include <hip/hip_runtime.h>
#include <math.h>

typedef __bf16 bfrag __attribute__((ext_vector_type(8)));
typedef __bf16 bf16x4 __attribute__((ext_vector_type(4)));
typedef __bf16 bf16x8 __attribute__((ext_vector_type(8)));
typedef float f32x4 __attribute__((ext_vector_type(4)));

// Problem constants
#define BN 32
#define HH 300
#define WW 300
#define HW 90000
#define NPX (BN * HW)

// Output tile 16 rows x 32 cols
#define GX 10   // ceil(300/32)
#define GY 19   // ceil(300/16)
#define CPX 612         // 18*34 c-tile pixels
#define XPX 720         // 20*36 staged pixels
#define CWSTRIDE 4896   // 612*8 shorts per channel-block array (fallback)

// ---------------- workspace layout (shared with fallback) ------------------
#define P5I_BYTE_OFF   0
#define P10I_BYTE_OFF  1843200
#define P15I_BYTE_OFF  2304000
#define CWB_BYTE_OFF   2508800
#define GWB_BYTE_OFF   2524160
#define STAT_BYTE_OFF  2531328
#define SS_BYTE_OFF    2539520
#define XBF_BYTE_OFF   2539584
#define XBF_END        (XBF_BYTE_OFF + (size_t)NPX * 16)   // 48,619,584
#define GW3_BYTE_OFF   XBF_END                              // gB3: [3][16][12][8] bf16
#define NEW3_END       (GW3_BYTE_OFF + 9216)                // 48,628,800

// ---------------- k_fused3 LDS layout (bytes) ------------------------------
#define XU3_OFF   0        // [20*36 px][8ch] bf16 = 11520
#define P5_OFF3   11520    // 5 rows x 8 cols x 16B = 640
#define P10_OFF3  12160    // 3 x 5 x 16B = 240
#define P15_OFF3  12400    // 3 x 4 x 16B = 192
#define CW0_OFF3  12592    // 612 px x 8ch bf16 = 9792
#define CW1_OFF3  22384    // 9792
#define LDS3_SIZE 32176    // <= 32768 -> 5 blocks/CU

__device__ __forceinline__ short f2bf(float f) {
    union { float f; unsigned u; } v;
    v.f = f;
    unsigned r = v.u + 0x7FFF + ((v.u >> 16) & 1);
    return (short)(r >> 16);
}

__device__ __forceinline__ float bf2f(unsigned short s) {
    union { unsigned u; float f; } v;
    v.u = ((unsigned)s) << 16;
    return v.f;
}

// ---------------------------------------------------------------------------
// setup: cB[s][n16][tap10][ci16] (n>=8 or tap==9 -> 0);
//        gB[n16][blk28][cj8] (fallback); gB3[s][n16][slot12][cj8] (slot>=9 -> 0)
// ---------------------------------------------------------------------------
__device__ __forceinline__ void setup_body(int gid, int gstride,
                                           const float* __restrict__ w5,
                                           const float* __restrict__ w10,
                                           const float* __restrict__ w15,
                                           const float* __restrict__ gw,
                                           const float* __restrict__ mw,
                                           short* __restrict__ cBg,
                                           short* __restrict__ gBg,
                                           short* __restrict__ gB3,
                                           double* __restrict__ stats) {
    for (int idx = gid; idx < 7680; idx += gstride) {
        int s = idx / 2560, rem = idx % 2560;
        int n = rem / 160, r2 = rem % 160;
        int tap = r2 / 16, ci = r2 % 16;
        float v = 0.f;
        if (n < 8 && tap < 9) {
            const float* W = (s == 0) ? w5 : ((s == 1) ? w10 : w15);
            v = W[(n * 16 + ci) * 9 + tap];
        }
        cBg[idx] = f2bf(v);
    }
    for (int idx = gid; idx < 3584; idx += gstride) {
        int n = idx / 224, r2 = idx % 224;
        int blk = r2 / 8, cj = r2 % 8;
        float v = 0.f;
        if (blk < 27) {
            int tap = blk / 3, ci24 = (blk % 3) * 8 + cj;
            if (n < 8) v = gw[(n * 24 + ci24) * 9 + tap];
            else       v = mw[((n - 8) * 24 + ci24) * 9 + tap];
        }
        gBg[idx] = f2bf(v);
    }
    if (gB3) {
        for (int idx = gid; idx < 4608; idx += gstride) {
            int s = idx / 1536, rem = idx % 1536;
            int n = rem / 96, r2 = rem % 96;
            int slot = r2 / 8, cj = r2 % 8;
            float v = 0.f;
            if (slot < 9) {
                int ci24 = s * 8 + cj;
                if (n < 8) v = gw[(n * 24 + ci24) * 9 + slot];
                else       v = mw[((n - 8) * 24 + ci24) * 9 + slot];
            }
            gB3[idx] = f2bf(v);
        }
    }
    for (int idx = gid; idx < 16 * 64; idx += gstride) stats[idx] = 0.0;
}

__global__ void k_setup(const float* __restrict__ w5, const float* __restrict__ w10,
                        const float* __restrict__ w15, const float* __restrict__ gw,
                        const float* __restrict__ mw, short* __restrict__ cBg,
                        short* __restrict__ gBg, double* __restrict__ stats) {
    setup_body(threadIdx.x, 256, w5, w10, w15, gw, mw, cBg, gBg, nullptr, stats);
}

// ---------------------------------------------------------------------------
// k_xbf: channel-interleaved bf16 copy of x; blocks (y==0,x<16) fold in setup
// ---------------------------------------------------------------------------
__global__ __launch_bounds__(256) void k_xbf(const float* __restrict__ x,
                                             unsigned short* __restrict__ xbf,
                                             const float* __restrict__ w5,
                                             const float* __restrict__ w10,
                                             const float* __restrict__ w15,
                                             const float* __restrict__ gw,
                                             const float* __restrict__ mw,
                                             short* __restrict__ cBg,
                                             short* __restrict__ gBg,
                                             short* __restrict__ gB3,
                                             double* __restrict__ stats) {
    const int b = blockIdx.y;
    const int px = blockIdx.x * 256 + threadIdx.x;
    if (px < HW) {
        const float* xp = x + (size_t)b * 8 * HW + px;
        bf16x8 pk;
#pragma unroll
        for (int ch = 0; ch < 8; ch++) pk[ch] = (__bf16)xp[(size_t)ch * HW];
        *(bf16x8*)&xbf[((size_t)b * HW + px) * 8] = pk;
    }
    if (blockIdx.y == 0 && blockIdx.x < 16) {
        int gid = blockIdx.x * 256 + threadIdx.x;
        setup_body(gid, 4096, w5, w10, w15, gw, mw, cBg, gBg, gB3, stats);
    }
}

// ---------------------------------------------------------------------------
// k_pool5b / k_poolD: pooled maps, interleaved [cells][8ch]
// ---------------------------------------------------------------------------
__global__ __launch_bounds__(256) void k_pool5b(const unsigned short* __restrict__ xbf,
                                                unsigned short* __restrict__ p5i) {
    int id = blockIdx.x * 256 + threadIdx.x;   // < 115200
    int b = id / 3600, cell = id % 3600;
    int pi = cell / 60, pj = cell % 60;
    const unsigned short* base = xbf + ((size_t)b * HW + pi * 5 * WW + pj * 5) * 8;
    float s[8] = {0.f, 0.f, 0.f, 0.f, 0.f, 0.f, 0.f, 0.f};
#pragma unroll
    for (int u = 0; u < 5; u++)
#pragma unroll
        for (int v = 0; v < 5; v++) {
            bf16x8 vv = *(const bf16x8*)&base[(u * WW + v) * 8];
#pragma unroll
            for (int ch = 0; ch < 8; ch++) s[ch] += (float)vv[ch];
        }
    bf16x8 pk;
#pragma unroll
    for (int ch = 0; ch < 8; ch++) pk[ch] = (__bf16)(s[ch] * 0.04f);
    *(bf16x8*)&p5i[((size_t)b * 3600 + cell) * 8] = pk;
}

__global__ void k_poolD(const unsigned short* __restrict__ p5i,
                        unsigned short* __restrict__ p10i,
                        unsigned short* __restrict__ p15i) {
    int id = blockIdx.x * 256 + threadIdx.x;
    if (id < 230400) {
        int bc = id / 900, cell = id % 900;
        int b = bc >> 3, c = bc & 7;
        int pi = cell / 30, pj = cell % 30;
        const unsigned short* base = p5i + ((size_t)b * 3600) * 8 + c;
        float s = bf2f(base[((2 * pi) * 60 + 2 * pj) * 8]) +
                  bf2f(base[((2 * pi) * 60 + 2 * pj + 1) * 8]) +
                  bf2f(base[((2 * pi + 1) * 60 + 2 * pj) * 8]) +
                  bf2f(base[((2 * pi + 1) * 60 + 2 * pj + 1) * 8]);
        p10i[((size_t)b * 900 + cell) * 8 + c] = (unsigned short)f2bf(s * 0.25f);
    } else if (id < 332800) {
        int id2 = id - 230400;
        int bc = id2 / 400, cell = id2 % 400;
        int b = bc >> 3, c = bc & 7;
        int pi = cell / 20, pj = cell % 20;
        const unsigned short* base = p5i + ((size_t)b * 3600) * 8 + c;
        float s = 0.f;
#pragma unroll
        for (int u = 0; u < 3; u++)
#pragma unroll
            for (int v = 0; v < 3; v++)
                s += bf2f(base[((3 * pi + u) * 60 + 3 * pj + v) * 8]);
        p15i[((size_t)b * 400 + cell) * 8 + c] = (unsigned short)f2bf(s * (1.f / 9.f));
    }
}

// ---------------------------------------------------------------------------
// c_phase3: conv([x, up_s]) -> cw buffer. x fragments from xuX; up fragments
// read pooled cells directly from a tiny LDS patch.
// ---------------------------------------------------------------------------
template <int K, int PCOLS>
__device__ __forceinline__ void c_phase3(char* LDSp, int cwOff, int patchOff,
                                         const unsigned short* __restrict__ cBs,
                                         const float* __restrict__ bias,
                                         int pr0, int pc0,
                                         int r0, int c0, int lane, int wid, bool edge) {
    constexpr int T0[5] = {0, 2, 4, 6, 8};   // qh=0 taps
    constexpr int T1[5] = {1, 3, 5, 7, 8};   // qh=1 taps (9 -> clamp 8 for addr)
    const int n = lane & 15, quad = lane >> 4;
    const int qh = quad >> 1, ql = quad & 1;
    bfrag wfr[5];
#pragma unroll
    for (int km = 0; km < 5; km++) {
        int tapw = km * 2 + qh;                 // 9 -> zero row in cB
        wfr[km] = *(const bfrag*)&cBs[(n * 10 + tapw) * 16 + ql * 8];
    }
    const int srow = patchOff - pr0 * (PCOLS * 16);  // scalar folds
    const int scol = -(pc0 << 4);
    float bO[4];
#pragma unroll
    for (int r = 0; r < 4; r++) bO[r] = bias[(quad & 1) * 4 + r];

    for (int g = wid; g < 39; g += 4) {
        int px = g * 16 + n;
        if (px > 611) px = 611;                 // dup lanes write same value
        int rp = (int)((unsigned)px / 34u);
        int cp = px - rp * 34;
        int xb = (rp * 36 + cp) * 16;
        int rowB[3], colB[3];
#pragma unroll
        for (int d = 0; d < 3; d++) {
            rowB[d] = (int)(((unsigned)(r0 - 2 + rp + d + K) / (unsigned)K) * (PCOLS * 16)) + srow;
            colB[d] = (int)(((unsigned)(c0 - 2 + cp + d + K) / (unsigned)K) << 4) + scol;
        }
        f32x4 acc = {0.f, 0.f, 0.f, 0.f};
#pragma unroll
        for (int km = 0; km < 5; km++) {
            int au0 = rowB[T0[km] / 3] + colB[T0[km] % 3];
            int au1 = rowB[T1[km] / 3] + colB[T1[km] % 3];
            int ax0 = xb + ((T0[km] / 3) * 36 + (T0[km] % 3)) * 16;
            int ax1 = xb + ((T1[km] / 3) * 36 + (T1[km] % 3)) * 16;
            int au = qh ? au1 : au0;
            int ax = qh ? ax1 : ax0;
            int ad = ql ? au : ax;
            acc = __builtin_amdgcn_mfma_f32_16x16x32_bf16(
                wfr[km], *(const bfrag*)(LDSp + ad), acc, 0, 0, 0);
        }
        if (quad < 2) {                          // channels quad*4+reg (0..7)
            bf16x4 pk;
#pragma unroll
            for (int r = 0; r < 4; r++) pk[r] = (__bf16)(acc[r] + bO[r]);
            if (edge) {
                int ra = r0 - 1 + rp, ca = c0 - 1 + cp;
                if (ra < 0 || ra >= HH || ca < 0 || ca >= WW) {
#pragma unroll
                    for (int r = 0; r < 4; r++) pk[r] = (__bf16)0.f;
                }
            }
            *(bf16x4*)(LDSp + cwOff + px * 16 + quad * 8) = pk;
        }
    }
}

// ---------------------------------------------------------------------------
// gate_partial: 3 K-MFMAs per group for one scale, accumulating into EIGHT
// NAMED f32x4 references (a0..a7). No local array, no address-taken
// aggregate -> SROA keeps every accumulator in VGPRs (round-6's f32x4*
// parameter spilled acc[8] to scratch: 400MB of HBM write traffic).
// ---------------------------------------------------------------------------
__device__ __forceinline__ void gate_partial(const char* LDSp, int cwOff,
                                             const unsigned short* __restrict__ gB3s,
                                             int lane, int wid,
                                             f32x4& a0, f32x4& a1, f32x4& a2, f32x4& a3,
                                             f32x4& a4, f32x4& a5, f32x4& a6, f32x4& a7) {
    const int n = lane & 15, quad = lane >> 4;
    bfrag gfr0, gfr1, gfr2;
    int go0, go1, go2;
    {
        int slot = quad;                        // 0..3
        gfr0 = *(const bfrag*)&gB3s[(n * 12 + slot) * 8];
        int di = slot / 3, dj = slot - di * 3;
        go0 = (di * 34 + dj) * 16;
    }
    {
        int slot = 4 + quad;                    // 4..7
        gfr1 = *(const bfrag*)&gB3s[(n * 12 + slot) * 8];
        int di = slot / 3, dj = slot - di * 3;
        go1 = (di * 34 + dj) * 16;
    }
    {
        int slot = 8 + quad;                    // 9..11 -> zero weights
        int tap = (slot > 8) ? 8 : slot;        // address clamp only
        gfr2 = *(const bfrag*)&gB3s[(n * 12 + slot) * 8];
        int di = tap / 3, dj = tap - di * 3;
        go2 = (di * 34 + dj) * 16;
    }
#define GATE_G(GI, A)                                                                        \
    {                                                                                        \
        int px = (wid + 4 * (GI)) * 16 + n;                                                  \
        int off0 = cwOff + ((px >> 5) * 34 + (px & 31)) * 16;                                \
        A = __builtin_amdgcn_mfma_f32_16x16x32_bf16(                                         \
            gfr0, *(const bfrag*)(LDSp + off0 + go0), A, 0, 0, 0);                           \
        A = __builtin_amdgcn_mfma_f32_16x16x32_bf16(                                         \
            gfr1, *(const bfrag*)(LDSp + off0 + go1), A, 0, 0, 0);                           \
        A = __builtin_amdgcn_mfma_f32_16x16x32_bf16(                                         \
            gfr2, *(const bfrag*)(LDSp + off0 + go2), A, 0, 0, 0);                           \
    }
    GATE_G(0, a0) GATE_G(1, a1) GATE_G(2, a2) GATE_G(3, a3)
    GATE_G(4, a4) GATE_G(5, a5) GATE_G(6, a6) GATE_G(7, a7)
#undef GATE_G
}

// ---------------------------------------------------------------------------
// k_fused3: 16x32 tile, LDS 32.2KB -> 5 blocks/CU (20 waves), 4 barriers.
// Per-scale gate accumulation overlaps gate(s) with c_phase(s+1).
// ---------------------------------------------------------------------------
__global__ __launch_bounds__(256, 5) void k_fused3(
    const unsigned short* __restrict__ xbf,
    const unsigned short* __restrict__ p5i, const unsigned short* __restrict__ p10i,
    const unsigned short* __restrict__ p15i,
    const unsigned short* __restrict__ cBg, const unsigned short* __restrict__ gB3,
    const float* __restrict__ b5, const float* __restrict__ b10, const float* __restrict__ b15,
    const float* __restrict__ gb, const float* __restrict__ mb,
    float* __restrict__ out, double* __restrict__ stats) {
    __shared__ __align__(16) char LDS[LDS3_SIZE];

    const int b = blockIdx.z;
    const int r0 = blockIdx.y * 16, c0 = blockIdx.x * 32;
    const int t = threadIdx.x, lane = t & 63, wid = t >> 6;
    const bool edge = (blockIdx.x == 0) | (blockIdx.x == GX - 1) |
                      (blockIdx.y == 0) | (blockIdx.y == GY - 1);

    const int pr0_5 = (r0 + 3) / 5, pc0_5 = (c0 + 3) / 5;
    const int pr0_10 = (r0 + 8) / 10, pc0_10 = (c0 + 8) / 10;
    const int pr0_15 = (r0 + 13) / 15, pc0_15 = (c0 + 13) / 15;

    // stage x tile (720 x uint4)
#pragma unroll
    for (int it = 0; it < 3; it++) {
        int idx = t + 256 * it;
        if (idx < XPX) {
            int i = idx / 36, j = idx - i * 36;
            int ra = r0 - 2 + i, ca = c0 - 2 + j;
            uint4 v = {0u, 0u, 0u, 0u};
            if (ra >= 0 && ra < HH && ca >= 0 && ca < WW)
                v = *(const uint4*)&xbf[((size_t)b * HW + ra * WW + ca) * 8];
            *(uint4*)(LDS + XU3_OFF + idx * 16) = v;
        }
    }
    // stage pooled patches (67 x uint4), zero-filled outside pooled grid
    if (t < 67) {
        const unsigned short* src;
        int off;
        bool valid;
        if (t < 40) {
            int a = t >> 3, cc = t & 7;
            int ci = pr0_5 - 1 + a, cj = pc0_5 - 1 + cc;
            valid = (ci >= 0) && (ci < 60) && (cj >= 0) && (cj < 60);
            src = p5i + ((size_t)b * 3600 + ci * 60 + cj) * 8;
            off = P5_OFF3 + t * 16;
        } else if (t < 55) {
            int i2 = t - 40;
            int a = i2 / 5, cc = i2 % 5;
            int ci = pr0_10 - 1 + a, cj = pc0_10 - 1 + cc;
            valid = (ci >= 0) && (ci < 30) && (cj >= 0) && (cj < 30);
            src = p10i + ((size_t)b * 900 + ci * 30 + cj) * 8;
            off = P10_OFF3 + i2 * 16;
        } else {
            int i2 = t - 55;
            int a = i2 >> 2, cc = i2 & 3;
            int ci = pr0_15 - 1 + a, cj = pc0_15 - 1 + cc;
            valid = (ci >= 0) && (ci < 20) && (cj >= 0) && (cj < 20);
            src = p15i + ((size_t)b * 400 + ci * 20 + cj) * 8;
            off = P15_OFF3 + i2 * 16;
        }
        uint4 v = {0u, 0u, 0u, 0u};
        if (valid) v = *(const uint4*)src;
        *(uint4*)(LDS + off) = v;
    }
    __syncthreads();

    f32x4 a0 = {0.f, 0.f, 0.f, 0.f}, a1 = a0, a2 = a0, a3 = a0;
    f32x4 a4 = a0, a5 = a0, a6 = a0, a7 = a0;

    c_phase3<5, 8>(LDS, CW0_OFF3, P5_OFF3, cBg, b5, pr0_5, pc0_5, r0, c0, lane, wid, edge);
    __syncthreads();
    gate_partial(LDS, CW0_OFF3, gB3, lane, wid, a0, a1, a2, a3, a4, a5, a6, a7);
    c_phase3<10, 5>(LDS, CW1_OFF3, P10_OFF3, cBg + 2560, b10, pr0_10, pc0_10, r0, c0, lane, wid, edge);
    __syncthreads();
    gate_partial(LDS, CW1_OFF3, gB3 + 1536, lane, wid, a0, a1, a2, a3, a4, a5, a6, a7);
    c_phase3<15, 4>(LDS, CW0_OFF3, P15_OFF3, cBg + 5120, b15, pr0_15, pc0_15, r0, c0, lane, wid, edge);
    __syncthreads();
    gate_partial(LDS, CW0_OFF3, gB3 + 3072, lane, wid, a0, a1, a2, a3, a4, a5, a6, a7);

    // epilogue: sigmoid on M-lanes (quads 2,3), pair via shfl_xor(32), store
    const int n = lane & 15, quad = lane >> 4;
    float gO[4], mO[4];
#pragma unroll
    for (int r = 0; r < 4; r++) {
        gO[r] = gb[(quad & 1) * 4 + r];
        mO[r] = mb[(quad & 1) * 4 + r];
    }
    float ls[4] = {0.f, 0.f, 0.f, 0.f}, ls2[4] = {0.f, 0.f, 0.f, 0.f};
#define EPI_G(GI, A)                                                                         \
    {                                                                                        \
        int px = (wid + 4 * (GI)) * 16 + n;                                                  \
        int rr = px >> 5, cc = px & 31;                                                      \
        int ra = r0 + rr, ca = c0 + cc;                                                      \
        bool wr = !edge || (ra < HH && ca < WW);                                             \
        _Pragma("unroll")                                                                    \
        for (int reg = 0; reg < 4; reg++) {                                                  \
            float val;                                                                       \
            if (quad < 2) val = A[reg] + gO[reg];                                            \
            else          val = __builtin_amdgcn_rcpf(1.f + __expf(-(A[reg] + mO[reg])));    \
            float other = __shfl_xor(val, 32);                                               \
            if (quad < 2 && wr) {                                                            \
                float y = val * other;                                                       \
                int ch = quad * 4 + reg;                                                     \
                out[(size_t)(b * 8 + ch) * HW + (size_t)ra * WW + ca] = y;                   \
                ls[reg] += y;                                                                \
                ls2[reg] += y * y;                                                           \
            }                                                                                \
        }                                                                                    \
    }
    EPI_G(0, a0) EPI_G(1, a1) EPI_G(2, a2) EPI_G(3, a3)
    EPI_G(4, a4) EPI_G(5, a5) EPI_G(6, a6) EPI_G(7, a7)
#undef EPI_G
#pragma unroll
    for (int m = 1; m < 16; m <<= 1) {
#pragma unroll
        for (int r = 0; r < 4; r++) {
            ls[r] += __shfl_xor(ls[r], m);
            ls2[r] += __shfl_xor(ls2[r], m);
        }
    }
    if (n == 0 && quad < 2) {
        int hash = (blockIdx.x + GX * blockIdx.y + GX * GY * blockIdx.z) & 63;
#pragma unroll
        for (int r = 0; r < 4; r++) {
            atomicAdd(&stats[(quad * 4 + r) * 64 + hash], (double)ls[r]);
            atomicAdd(&stats[(8 + quad * 4 + r) * 64 + hash], (double)ls2[r]);
        }
    }
}

// ===========================================================================
// ============ fallback (round-4) kernels, unchanged ========================
// ===========================================================================
__global__ void k_pool5(const float* __restrict__ x, unsigned short* __restrict__ p5i) {
    int id = blockIdx.x * 256 + threadIdx.x;
    int bc = id / 3600, cell = id % 3600;
    int b = bc >> 3, c = bc & 7;
    int pi = cell / 60, pj = cell % 60;
    const float* rp = x + (size_t)bc * HW + pi * 5 * WW + pj * 5;
    float s = 0.f;
#pragma unroll
    for (int u = 0; u < 5; u++)
#pragma unroll
        for (int v = 0; v < 5; v++) s += rp[u * WW + v];
    p5i[((size_t)b * 3600 + cell) * 8 + c] = (unsigned short)f2bf(s * 0.04f);
}

template <int K, int PW>
__device__ __forceinline__ void up_load(const unsigned short* __restrict__ pooled,
                                        int b, int r0, int c0, int t, uint4* v) {
#pragma unroll
    for (int it = 0; it < 3; it++) {
        int idx = t + 256 * it;
        uint4 val = {0u, 0u, 0u, 0u};
        if (idx < XPX) {
            int i = idx / 36, j = idx - i * 36;
            int ra = r0 - 2 + i, ca = c0 - 2 + j;
            if (ra >= 0 && ra < HH && ca >= 0 && ca < WW) {
                int pi = (int)((unsigned)ra / K);
                int pj = (int)((unsigned)ca / K);
                val = *(const uint4*)&pooled[((size_t)b * (PW * PW) + pi * PW + pj) * 8];
            }
        }
        v[it] = val;
    }
}

__device__ __forceinline__ void up_store(short* xuU, int t, const uint4* v) {
#pragma unroll
    for (int it = 0; it < 3; it++) {
        int idx = t + 256 * it;
        if (idx < XPX) *(uint4*)&xuU[idx * 8] = v[it];
    }
}

__device__ __forceinline__ void c_phase(const short* xuX, const short* xuU,
                                        short* cwP,
                                        const unsigned short* __restrict__ cBs,
                                        const float* __restrict__ bias,
                                        int r0, int c0, int lane, int wid, bool edge) {
    const int n = lane & 15, quad = lane >> 4;
    const int qh = quad >> 1, ql = quad & 1;
    const short* xbase = ql ? xuU : xuX;
    bfrag wfr[5];
    int dpoff[5];
#pragma unroll
    for (int km = 0; km < 5; km++) {
        int tapw = km * 2 + qh;
        int tapa = (tapw > 8) ? 8 : tapw;
        wfr[km] = *(const bfrag*)&cBs[(n * 10 + tapw) * 16 + ql * 8];
        dpoff[km] = ((tapa / 3) * 36 + tapa % 3) * 8;
    }
    float bO[4];
#pragma unroll
    for (int r = 0; r < 4; r++) bO[r] = bias[(quad & 1) * 4 + r];

    for (int g = wid; g < 39; g += 4) {
        int px = g * 16 + n;
        if (px > 611) px = 611;
        int rp = (int)((unsigned)px / 34u);
        int cp = px - rp * 34;
        int pb = (rp * 36 + cp) * 8;
        f32x4 acc = {0.f, 0.f, 0.f, 0.f};
#pragma unroll
        for (int km = 0; km < 5; km++)
            acc = __builtin_amdgcn_mfma_f32_16x16x32_bf16(
                wfr[km], *(const bfrag*)&xbase[pb + dpoff[km]], acc, 0, 0, 0);
        if (quad < 2) {
            bf16x4 pk;
#pragma unroll
            for (int r = 0; r < 4; r++) pk[r] = (__bf16)(acc[r] + bO[r]);
            if (edge) {
                int ra = r0 - 1 + rp, ca = c0 - 1 + cp;
                if (ra < 0 || ra >= HH || ca < 0 || ca >= WW) {
#pragma unroll
                    for (int r = 0; r < 4; r++) pk[r] = (__bf16)0.f;
                }
            }
            *(bf16x4*)&cwP[px * 8 + quad * 4] = pk;
        }
    }
}

template <bool XBF>
__global__ __launch_bounds__(256, 3) void k_fused(
    const float* __restrict__ x, const unsigned short* __restrict__ xbf,
    const unsigned short* __restrict__ p5i, const unsigned short* __restrict__ p10i,
    const unsigned short* __restrict__ p15i,
    const unsigned short* __restrict__ cBg, const unsigned short* __restrict__ gBg,
    const float* __restrict__ b5, const float* __restrict__ b10, const float* __restrict__ b15,
    const float* __restrict__ gb, const float* __restrict__ mb,
    float* __restrict__ out, double* __restrict__ stats) {
    __shared__ __align__(16) short xuX[XPX * 8];
    __shared__ __align__(16) short xuU[XPX * 8];
    __shared__ __align__(16) short cwS[3 * CWSTRIDE];

    const int b = blockIdx.z;
    const int r0 = blockIdx.y * 16, c0 = blockIdx.x * 32;
    const int t = threadIdx.x, lane = t & 63, wid = t >> 6;
    const bool edge = (blockIdx.x == 0) | (blockIdx.x == GX - 1) |
                      (blockIdx.y == 0) | (blockIdx.y == GY - 1);

    uint4 upv[3];
    up_load<5, 60>(p5i, b, r0, c0, t, upv);

    if constexpr (XBF) {
#pragma unroll
        for (int it = 0; it < 3; it++) {
            int idx = t + 256 * it;
            if (idx < XPX) {
                int i = idx / 36, j = idx - i * 36;
                int ra = r0 - 2 + i, ca = c0 - 2 + j;
                uint4 v = {0u, 0u, 0u, 0u};
                if (ra >= 0 && ra < HH && ca >= 0 && ca < WW)
                    v = *(const uint4*)&xbf[((size_t)b * HW + ra * WW + ca) * 8];
                *(uint4*)&xuX[idx * 8] = v;
            }
        }
    } else {
        for (int idx = t; idx < 1440; idx += 256) {
            int cp = idx / 360, rem = idx % 360;
            int i = rem / 18, jp = rem % 18;
            int j = 2 * jp;
            int ra = r0 - 2 + i, ca = c0 - 2 + j;
            float2 v0 = {0.f, 0.f}, v1 = {0.f, 0.f};
            if (ra >= 0 && ra < HH && ca >= 0 && ca <= WW - 2) {
                size_t base = ((size_t)(b * 8 + 2 * cp) * HH + ra) * WW + ca;
                v0 = *(const float2*)&x[base];
                v1 = *(const float2*)&x[base + HW];
            }
            unsigned pA = (unsigned short)f2bf(v0.x) | ((unsigned)(unsigned short)f2bf(v1.x) << 16);
            unsigned pB = (unsigned short)f2bf(v0.y) | ((unsigned)(unsigned short)f2bf(v1.y) << 16);
            int px = i * 36 + j;
            *(unsigned*)&xuX[px * 8 + 2 * cp] = pA;
            *(unsigned*)&xuX[(px + 1) * 8 + 2 * cp] = pB;
        }
    }
    up_store(xuU, t, upv);
    __syncthreads();

    c_phase(xuX, xuU, cwS, cBg, b5, r0, c0, lane, wid, edge);
    up_load<10, 30>(p10i, b, r0, c0, t, upv);
    __syncthreads();
    up_store(xuU, t, upv);
    __syncthreads();

    c_phase(xuX, xuU, cwS + CWSTRIDE, cBg + 2560, b10, r0, c0, lane, wid, edge);
    up_load<15, 20>(p15i, b, r0, c0, t, upv);
    __syncthreads();
    up_store(xuU, t, upv);
    __syncthreads();

    c_phase(xuX, xuU, cwS + 2 * CWSTRIDE, cBg + 5120, b15, r0, c0, lane, wid, edge);
    __syncthreads();

    const int n = lane & 15, quad = lane >> 4;
    bfrag gfr[7];
    int goff[7];
#pragma unroll
    for (int km = 0; km < 7; km++) {
        int blkw = km * 4 + quad;
        int blka = (blkw > 26) ? 26 : blkw;
        gfr[km] = *(const bfrag*)&gBg[(n * 28 + blkw) * 8];
        int tap = blka / 3, cig = blka - tap * 3;
        goff[km] = cig * CWSTRIDE + ((tap / 3) * 34 + tap % 3) * 8;
    }
    float gO[4], mO[4];
#pragma unroll
    for (int r = 0; r < 4; r++) {
        gO[r] = gb[(quad & 1) * 4 + r];
        mO[r] = mb[(quad & 1) * 4 + r];
    }
    float ls[4] = {0.f, 0.f, 0.f, 0.f}, ls2[4] = {0.f, 0.f, 0.f, 0.f};

    for (int g = wid; g < 32; g += 4) {
        int px = g * 16 + n;
        int rr = px >> 5, cc = px & 31;
        int off0 = (rr * 34 + cc) * 8;
        f32x4 acc = {0.f, 0.f, 0.f, 0.f};
#pragma unroll
        for (int km = 0; km < 7; km++)
            acc = __builtin_amdgcn_mfma_f32_16x16x32_bf16(
                gfr[km], *(const bfrag*)&cwS[off0 + goff[km]], acc, 0, 0, 0);
        int ra = r0 + rr, ca = c0 + cc;
        bool wr = !edge || (ra < HH && ca < WW);
#pragma unroll
        for (int reg = 0; reg < 4; reg++) {
            float val;
            if (quad < 2) val = acc[reg] + gO[reg];
            else          val = __builtin_amdgcn_rcpf(1.f + __expf(-(acc[reg] + mO[reg])));
            float other = __shfl_xor(val, 32);
            if (quad < 2 && wr) {
                float y = val * other;
                int ch = quad * 4 + reg;
                out[(size_t)(b * 8 + ch) * HW + (size_t)ra * WW + ca] = y;
                ls[reg] += y;
                ls2[reg] += y * y;
            }
        }
    }
#pragma unroll
    for (int m = 1; m < 16; m <<= 1) {
#pragma unroll
        for (int r = 0; r < 4; r++) {
            ls[r] += __shfl_xor(ls[r], m);
            ls2[r] += __shfl_xor(ls2[r], m);
        }
    }
    if (n == 0 && quad < 2) {
        int hash = (blockIdx.x + GX * blockIdx.y + GX * GY * blockIdx.z) & 63;
#pragma unroll
        for (int r = 0; r < 4; r++) {
            atomicAdd(&stats[(quad * 4 + r) * 64 + hash], (double)ls[r]);
            atomicAdd(&stats[(8 + quad * 4 + r) * 64 + hash], (double)ls2[r]);
        }
    }
}

// ---------------------------------------------------------------------------
__global__ void k_stats(const double* __restrict__ stats, const float* __restrict__ gamma,
                        const float* __restrict__ beta, float* __restrict__ ss) {
    __shared__ double red[16][16];
    int t = threadIdx.x;
    int row = t >> 4, col = t & 15;
    double s = stats[row * 64 + col] + stats[row * 64 + col + 16] +
               stats[row * 64 + col + 32] + stats[row * 64 + col + 48];
    red[row][col] = s;
    __syncthreads();
    if (t < 16) {
        double tot = 0.0;
#pragma unroll
        for (int i = 0; i < 16; i++) tot += red[t][i];
        red[t][0] = tot;
    }
    __syncthreads();
    if (t < 8) {
        double N = (double)NPX;
        double mean = red[t][0] / N;
        double var = red[8 + t][0] / N - mean * mean;
        double scale = (double)gamma[t] / sqrt(var + 1e-5);
        ss[t] = (float)scale;
        ss[8 + t] = (float)((double)beta[t] - mean * scale);
    }
}

__global__ void k_norm(float* __restrict__ out, const float* __restrict__ ss) {
    int i = blockIdx.x * 256 + threadIdx.x;
    if (i < (BN * 8 * HW) / 4) {
        int plane = (i * 4) / HW;
        int ch = plane & 7;
        float sc = ss[ch], sh = ss[8 + ch];
        float4* p = (float4*)out + i;
        float4 v = *p;
        v.x = v.x * sc + sh;
        v.y = v.y * sc + sh;
        v.z = v.z * sc + sh;
        v.w = v.w * sc + sh;
        *p = v;
    }
}

// ---------------------------------------------------------------------------
extern "C" void kernel_launch(void* const* d_in, const int* in_sizes, int n_in,
                              void* d_out, int out_size, void* d_ws, size_t ws_size,
                              hipStream_t stream) {
    const float* x = (const float*)d_in[0];
    const float* w5 = (const float*)d_in[1];
    const float* b5 = (const float*)d_in[2];
    const float* w10 = (const float*)d_in[3];
    const float* b10 = (const float*)d_in[4];
    const float* w15 = (const float*)d_in[5];
    const float* b15 = (const float*)d_in[6];
    const float* gw = (const float*)d_in[7];
    const float* gb = (const float*)d_in[8];
    const float* mw = (const float*)d_in[9];
    const float* mb = (const float*)d_in[10];
    const float* gamma = (const float*)d_in[11];
    const float* beta = (const float*)d_in[12];
    float* out = (float*)d_out;

    unsigned short* p5i = (unsigned short*)((char*)d_ws + P5I_BYTE_OFF);
    unsigned short* p10i = (unsigned short*)((char*)d_ws + P10I_BYTE_OFF);
    unsigned short* p15i = (unsigned short*)((char*)d_ws + P15I_BYTE_OFF);
    short* cBg = (short*)((char*)d_ws + CWB_BYTE_OFF);
    short* gBg = (short*)((char*)d_ws + GWB_BYTE_OFF);
    double* stats = (double*)((char*)d_ws + STAT_BYTE_OFF);
    float* ss = (float*)((char*)d_ws + SS_BYTE_OFF);
    unsigned short* xbf = (unsigned short*)((char*)d_ws + XBF_BYTE_OFF);
    short* gB3 = (short*)((char*)d_ws + GW3_BYTE_OFF);

    dim3 grid(GX, GY, BN);
    if (ws_size >= NEW3_END) {
        k_xbf<<<dim3(352, 32), 256, 0, stream>>>(x, xbf, w5, w10, w15, gw, mw,
                                                 cBg, gBg, gB3, stats);
        k_pool5b<<<450, 256, 0, stream>>>(xbf, p5i);
        k_poolD<<<1300, 256, 0, stream>>>(p5i, p10i, p15i);
        k_fused3<<<grid, 256, 0, stream>>>(xbf, p5i, p10i, p15i,
                                           (const unsigned short*)cBg, (const unsigned short*)gB3,
                                           b5, b10, b15, gb, mb, out, stats);
    } else if (ws_size >= XBF_END) {
        k_xbf<<<dim3(352, 32), 256, 0, stream>>>(x, xbf, w5, w10, w15, gw, mw,
                                                 cBg, gBg, nullptr, stats);
        k_pool5b<<<450, 256, 0, stream>>>(xbf, p5i);
        k_poolD<<<1300, 256, 0, stream>>>(p5i, p10i, p15i);
        k_fused<true><<<grid, 256, 0, stream>>>(x, xbf, p5i, p10i, p15i,
                                                (const unsigned short*)cBg, (const unsigned short*)gBg,
                                                b5, b10, b15, gb, mb, out, stats);
    } else {
        k_setup<<<1, 256, 0, stream>>>(w5, w10, w15, gw, mw, cBg, gBg, stats);
        k_pool5<<<3600, 256, 0, stream>>>(x, p5i);
        k_poolD<<<1300, 256, 0, stream>>>(p5i, p10i, p15i);
        k_fused<false><<<grid, 256, 0, stream>>>(x, xbf, p5i, p10i, p15i,
                                                 (const unsigned short*)cBg, (const unsigned short*)gBg,
                                                 b5, b10, b15, gb, mb, out, stats);
    }
    k_stats<<<1, 256, 0, stream>>>(stats, gamma, beta, ss);
    k_norm<<<(BN * 8 * HW / 4 + 255) / 256, 256, 0, stream>>>(out, ss);
}

// Round 9
// 383.550 us; speedup vs baseline: 1.8406x; 1.8406x over previous
//
#include <hip/hip_runtime.h>
#include <math.h>

typedef __bf16 bfrag __attribute__((ext_vector_type(8)));
typedef __bf16 bf16x4 __attribute__((ext_vector_type(4)));
typedef __bf16 bf16x8 __attribute__((ext_vector_type(8)));
typedef float f32x4 __attribute__((ext_vector_type(4)));

// Problem constants
#define BN 32
#define HH 300
#define WW 300
#define HW 90000
#define NPX (BN * HW)

// Output tile 16 rows x 32 cols
#define GX 10   // ceil(300/32)
#define GY 19   // ceil(300/16)
#define CPX 612         // 18*34 c-tile pixels
#define XPX 720         // 20*36 staged pixels
#define CWSTRIDE 4896   // 612*8 shorts per channel-block array (fallback)

// ---------------- workspace layout ----------------
#define P5I_BYTE_OFF   0
#define P10I_BYTE_OFF  1843200
#define P15I_BYTE_OFF  2304000
#define CWB_BYTE_OFF   2508800
#define GWB_BYTE_OFF   2524160
#define STAT_BYTE_OFF  2531328
#define SS_BYTE_OFF    2539520
#define XBF_BYTE_OFF   2539584
#define XBF_END        (XBF_BYTE_OFF + (size_t)NPX * 16)   // 48,619,584

// ---------------- k_fused4 LDS layout (bytes) ------------------------------
#define XU4_OFF   0        // [20*36 px][8ch] bf16 = 11520
#define P5_OFF4   11520    // 5 rows x 8 cols x 16B = 640
#define P10_OFF4  12160    // 3 x 5 x 16B = 240
#define P15_OFF4  12400    // 3 x 4 x 16B = 192
#define CW4_OFF   12592    // [3][612 px][8ch] bf16 = 29376
#define LDS4_SIZE 41968    // -> 3 blocks/CU

__device__ __forceinline__ short f2bf(float f) {
    union { float f; unsigned u; } v;
    v.f = f;
    unsigned r = v.u + 0x7FFF + ((v.u >> 16) & 1);
    return (short)(r >> 16);
}

__device__ __forceinline__ float bf2f(unsigned short s) {
    union { unsigned u; float f; } v;
    v.u = ((unsigned)s) << 16;
    return v.f;
}

// ---------------------------------------------------------------------------
// setup: cB[s][n16][tap10][ci16] (n>=8 or tap==9 -> 0);
//        gB[n16][blk28][cj8] (blk>=27 -> 0); zero stat bins
// ---------------------------------------------------------------------------
__device__ __forceinline__ void setup_body(int gid, int gstride,
                                           const float* __restrict__ w5,
                                           const float* __restrict__ w10,
                                           const float* __restrict__ w15,
                                           const float* __restrict__ gw,
                                           const float* __restrict__ mw,
                                           short* __restrict__ cBg,
                                           short* __restrict__ gBg,
                                           double* __restrict__ stats) {
    for (int idx = gid; idx < 7680; idx += gstride) {
        int s = idx / 2560, rem = idx % 2560;
        int n = rem / 160, r2 = rem % 160;
        int tap = r2 / 16, ci = r2 % 16;
        float v = 0.f;
        if (n < 8 && tap < 9) {
            const float* W = (s == 0) ? w5 : ((s == 1) ? w10 : w15);
            v = W[(n * 16 + ci) * 9 + tap];
        }
        cBg[idx] = f2bf(v);
    }
    for (int idx = gid; idx < 3584; idx += gstride) {
        int n = idx / 224, r2 = idx % 224;
        int blk = r2 / 8, cj = r2 % 8;
        float v = 0.f;
        if (blk < 27) {
            int tap = blk / 3, ci24 = (blk % 3) * 8 + cj;
            if (n < 8) v = gw[(n * 24 + ci24) * 9 + tap];
            else       v = mw[((n - 8) * 24 + ci24) * 9 + tap];
        }
        gBg[idx] = f2bf(v);
    }
    for (int idx = gid; idx < 16 * 64; idx += gstride) stats[idx] = 0.0;
}

__global__ void k_setup(const float* __restrict__ w5, const float* __restrict__ w10,
                        const float* __restrict__ w15, const float* __restrict__ gw,
                        const float* __restrict__ mw, short* __restrict__ cBg,
                        short* __restrict__ gBg, double* __restrict__ stats) {
    setup_body(threadIdx.x, 256, w5, w10, w15, gw, mw, cBg, gBg, stats);
}

// ---------------------------------------------------------------------------
// k_xbf: channel-interleaved bf16 copy of x; blocks (y==0,x<16) fold in setup
// ---------------------------------------------------------------------------
__global__ __launch_bounds__(256) void k_xbf(const float* __restrict__ x,
                                             unsigned short* __restrict__ xbf,
                                             const float* __restrict__ w5,
                                             const float* __restrict__ w10,
                                             const float* __restrict__ w15,
                                             const float* __restrict__ gw,
                                             const float* __restrict__ mw,
                                             short* __restrict__ cBg,
                                             short* __restrict__ gBg,
                                             double* __restrict__ stats) {
    const int b = blockIdx.y;
    const int px = blockIdx.x * 256 + threadIdx.x;
    if (px < HW) {
        const float* xp = x + (size_t)b * 8 * HW + px;
        bf16x8 pk;
#pragma unroll
        for (int ch = 0; ch < 8; ch++) pk[ch] = (__bf16)xp[(size_t)ch * HW];
        *(bf16x8*)&xbf[((size_t)b * HW + px) * 8] = pk;
    }
    if (blockIdx.y == 0 && blockIdx.x < 16) {
        int gid = blockIdx.x * 256 + threadIdx.x;
        setup_body(gid, 4096, w5, w10, w15, gw, mw, cBg, gBg, stats);
    }
}

// ---------------------------------------------------------------------------
// k_poolAll: one dispatch builds p5, p10, p15. Block = 6x6 p5-cell region
// (30x30 px) of one batch; p10 (3x3) and p15 (2x2) derive from the LDS p5
// tile (region boundaries align: 6 = lcm alignment for 2x2 and 3x3 grouping).
// ---------------------------------------------------------------------------
__global__ __launch_bounds__(256) void k_poolAll(const unsigned short* __restrict__ xbf,
                                                 unsigned short* __restrict__ p5i,
                                                 unsigned short* __restrict__ p10i,
                                                 unsigned short* __restrict__ p15i) {
    __shared__ __align__(16) short xt[900 * 8];  // 30x30 px x 8ch bf16
    __shared__ float p5t[36][8];
    const int b = blockIdx.y;
    const int bi = blockIdx.x / 10, bj = blockIdx.x % 10;
    const int t = threadIdx.x;
    for (int idx = t; idx < 900; idx += 256) {
        int r = idx / 30, c = idx - r * 30;
        *(uint4*)&xt[idx * 8] =
            *(const uint4*)&xbf[((size_t)b * HW + (bi * 30 + r) * WW + bj * 30 + c) * 8];
    }
    __syncthreads();
    if (t < 36) {
        int pi = t / 6, pj = t - (t / 6) * 6;
        float s[8] = {0.f, 0.f, 0.f, 0.f, 0.f, 0.f, 0.f, 0.f};
#pragma unroll
        for (int u = 0; u < 5; u++)
#pragma unroll
            for (int v = 0; v < 5; v++) {
                bf16x8 vv = *(const bf16x8*)&xt[((pi * 5 + u) * 30 + pj * 5 + v) * 8];
#pragma unroll
                for (int ch = 0; ch < 8; ch++) s[ch] += (float)vv[ch];
            }
        bf16x8 pk;
#pragma unroll
        for (int ch = 0; ch < 8; ch++) {
            float av = s[ch] * 0.04f;
            p5t[t][ch] = av;
            pk[ch] = (__bf16)av;
        }
        *(bf16x8*)&p5i[((size_t)b * 3600 + (bi * 6 + pi) * 60 + bj * 6 + pj) * 8] = pk;
    }
    __syncthreads();
    if (t < 9) {        // p10: 3x3 cells, each = 2x2 p5 cells (exact mean)
        int pi = t / 3, pj = t - (t / 3) * 3;
        bf16x8 pk;
#pragma unroll
        for (int ch = 0; ch < 8; ch++) {
            float s = p5t[(2 * pi) * 6 + 2 * pj][ch] + p5t[(2 * pi) * 6 + 2 * pj + 1][ch] +
                      p5t[(2 * pi + 1) * 6 + 2 * pj][ch] + p5t[(2 * pi + 1) * 6 + 2 * pj + 1][ch];
            pk[ch] = (__bf16)(s * 0.25f);
        }
        *(bf16x8*)&p10i[((size_t)b * 900 + (bi * 3 + pi) * 30 + bj * 3 + pj) * 8] = pk;
    } else if (t < 13) {  // p15: 2x2 cells, each = 3x3 p5 cells
        int i2 = t - 9;
        int pi = i2 >> 1, pj = i2 & 1;
        bf16x8 pk;
#pragma unroll
        for (int ch = 0; ch < 8; ch++) {
            float s = 0.f;
#pragma unroll
            for (int u = 0; u < 3; u++)
#pragma unroll
                for (int v = 0; v < 3; v++) s += p5t[(3 * pi + u) * 6 + 3 * pj + v][ch];
            pk[ch] = (__bf16)(s * (1.f / 9.f));
        }
        *(bf16x8*)&p15i[((size_t)b * 400 + (bi * 2 + pi) * 20 + bj * 2 + pj) * 8] = pk;
    }
}

// ---------------------------------------------------------------------------
// c_phase3: conv([x, up_s]) -> cw buffer; x fragments from xuX, up fragments
// from tiny LDS pooled patches (address math HW-verified in round 8).
// ---------------------------------------------------------------------------
template <int K, int PCOLS>
__device__ __forceinline__ void c_phase3(char* LDSp, int cwOff, int patchOff,
                                         const unsigned short* __restrict__ cBs,
                                         const float* __restrict__ bias,
                                         int pr0, int pc0,
                                         int r0, int c0, int lane, int wid, bool edge) {
    constexpr int T0[5] = {0, 2, 4, 6, 8};   // qh=0 taps
    constexpr int T1[5] = {1, 3, 5, 7, 8};   // qh=1 taps (9 -> clamp 8 for addr)
    const int n = lane & 15, quad = lane >> 4;
    const int qh = quad >> 1, ql = quad & 1;
    bfrag wfr[5];
#pragma unroll
    for (int km = 0; km < 5; km++) {
        int tapw = km * 2 + qh;                 // 9 -> zero row in cB
        wfr[km] = *(const bfrag*)&cBs[(n * 10 + tapw) * 16 + ql * 8];
    }
    const int srow = patchOff - pr0 * (PCOLS * 16);  // scalar folds
    const int scol = -(pc0 << 4);
    float bO[4];
#pragma unroll
    for (int r = 0; r < 4; r++) bO[r] = bias[(quad & 1) * 4 + r];

    for (int g = wid; g < 39; g += 4) {
        int px = g * 16 + n;
        if (px > 611) px = 611;                 // dup lanes write same value
        int rp = (int)((unsigned)px / 34u);
        int cp = px - rp * 34;
        int xb = (rp * 36 + cp) * 16;
        int rowB[3], colB[3];
#pragma unroll
        for (int d = 0; d < 3; d++) {
            rowB[d] = (int)(((unsigned)(r0 - 2 + rp + d + K) / (unsigned)K) * (PCOLS * 16)) + srow;
            colB[d] = (int)(((unsigned)(c0 - 2 + cp + d + K) / (unsigned)K) << 4) + scol;
        }
        f32x4 acc = {0.f, 0.f, 0.f, 0.f};
#pragma unroll
        for (int km = 0; km < 5; km++) {
            int au0 = rowB[T0[km] / 3] + colB[T0[km] % 3];
            int au1 = rowB[T1[km] / 3] + colB[T1[km] % 3];
            int ax0 = xb + ((T0[km] / 3) * 36 + (T0[km] % 3)) * 16;
            int ax1 = xb + ((T1[km] / 3) * 36 + (T1[km] % 3)) * 16;
            int au = qh ? au1 : au0;
            int ax = qh ? ax1 : ax0;
            int ad = ql ? au : ax;
            acc = __builtin_amdgcn_mfma_f32_16x16x32_bf16(
                wfr[km], *(const bfrag*)(LDSp + ad), acc, 0, 0, 0);
        }
        if (quad < 2) {                          // channels quad*4+reg (0..7)
            bf16x4 pk;
#pragma unroll
            for (int r = 0; r < 4; r++) pk[r] = (__bf16)(acc[r] + bO[r]);
            if (edge) {
                int ra = r0 - 1 + rp, ca = c0 - 1 + cp;
                if (ra < 0 || ra >= HH || ca < 0 || ca >= WW) {
#pragma unroll
                    for (int r = 0; r < 4; r++) pk[r] = (__bf16)0.f;
                }
            }
            *(bf16x4*)(LDSp + cwOff + px * 16 + quad * 8) = pk;
        }
    }
}

// ---------------------------------------------------------------------------
// k_fused4: 16x32 tile, round-4 structure minus the up staging.
// LDS 41.9KB -> 3 blocks/CU; only TWO barriers (stage -> c-phases -> gate).
// No persistent accumulators across phases; launch_bounds (256,3) -> VGPR
// cap 170 (rounds 6/8 spilled under the (256,5) cap of ~96).
// ---------------------------------------------------------------------------
__global__ __launch_bounds__(256, 3) void k_fused4(
    const unsigned short* __restrict__ xbf,
    const unsigned short* __restrict__ p5i, const unsigned short* __restrict__ p10i,
    const unsigned short* __restrict__ p15i,
    const unsigned short* __restrict__ cBg, const unsigned short* __restrict__ gBg,
    const float* __restrict__ b5, const float* __restrict__ b10, const float* __restrict__ b15,
    const float* __restrict__ gb, const float* __restrict__ mb,
    float* __restrict__ out, double* __restrict__ stats) {
    __shared__ __align__(16) char LDS[LDS4_SIZE];

    const int b = blockIdx.z;
    const int r0 = blockIdx.y * 16, c0 = blockIdx.x * 32;
    const int t = threadIdx.x, lane = t & 63, wid = t >> 6;
    const bool edge = (blockIdx.x == 0) | (blockIdx.x == GX - 1) |
                      (blockIdx.y == 0) | (blockIdx.y == GY - 1);

    const int pr0_5 = (r0 + 3) / 5, pc0_5 = (c0 + 3) / 5;
    const int pr0_10 = (r0 + 8) / 10, pc0_10 = (c0 + 8) / 10;
    const int pr0_15 = (r0 + 13) / 15, pc0_15 = (c0 + 13) / 15;

    // stage x tile (720 x uint4)
#pragma unroll
    for (int it = 0; it < 3; it++) {
        int idx = t + 256 * it;
        if (idx < XPX) {
            int i = idx / 36, j = idx - i * 36;
            int ra = r0 - 2 + i, ca = c0 - 2 + j;
            uint4 v = {0u, 0u, 0u, 0u};
            if (ra >= 0 && ra < HH && ca >= 0 && ca < WW)
                v = *(const uint4*)&xbf[((size_t)b * HW + ra * WW + ca) * 8];
            *(uint4*)(LDS + XU4_OFF + idx * 16) = v;
        }
    }
    // stage pooled patches (67 x uint4), zero-filled outside pooled grid
    if (t < 67) {
        const unsigned short* src;
        int off;
        bool valid;
        if (t < 40) {
            int a = t >> 3, cc = t & 7;
            int ci = pr0_5 - 1 + a, cj = pc0_5 - 1 + cc;
            valid = (ci >= 0) && (ci < 60) && (cj >= 0) && (cj < 60);
            src = p5i + ((size_t)b * 3600 + ci * 60 + cj) * 8;
            off = P5_OFF4 + t * 16;
        } else if (t < 55) {
            int i2 = t - 40;
            int a = i2 / 5, cc = i2 % 5;
            int ci = pr0_10 - 1 + a, cj = pc0_10 - 1 + cc;
            valid = (ci >= 0) && (ci < 30) && (cj >= 0) && (cj < 30);
            src = p10i + ((size_t)b * 900 + ci * 30 + cj) * 8;
            off = P10_OFF4 + i2 * 16;
        } else {
            int i2 = t - 55;
            int a = i2 >> 2, cc = i2 & 3;
            int ci = pr0_15 - 1 + a, cj = pc0_15 - 1 + cc;
            valid = (ci >= 0) && (ci < 20) && (cj >= 0) && (cj < 20);
            src = p15i + ((size_t)b * 400 + ci * 20 + cj) * 8;
            off = P15_OFF4 + i2 * 16;
        }
        uint4 v = {0u, 0u, 0u, 0u};
        if (valid) v = *(const uint4*)src;
        *(uint4*)(LDS + off) = v;
    }
    __syncthreads();

    // three c-phases, disjoint cwS regions, no barriers between them
    c_phase3<5, 8>(LDS, CW4_OFF,          P5_OFF4,  cBg,        b5,  pr0_5,  pc0_5,  r0, c0, lane, wid, edge);
    c_phase3<10, 5>(LDS, CW4_OFF + 9792,  P10_OFF4, cBg + 2560, b10, pr0_10, pc0_10, r0, c0, lane, wid, edge);
    c_phase3<15, 4>(LDS, CW4_OFF + 19584, P15_OFF4, cBg + 5120, b15, pr0_15, pc0_15, r0, c0, lane, wid, edge);
    __syncthreads();

    // gate phase (round-4 proven): A = gB weights (G 0-7 / M 8-15), B = cwS
    // pixels across all 27 (tap, scale) blocks; sigmoid on idle M-lanes.
    const int n = lane & 15, quad = lane >> 4;
    bfrag gfr[7];
    int goff[7];
#pragma unroll
    for (int km = 0; km < 7; km++) {
        int blkw = km * 4 + quad;               // 27 -> zero block in gB
        int blka = (blkw > 26) ? 26 : blkw;     // address clamp only
        gfr[km] = *(const bfrag*)&gBg[(n * 28 + blkw) * 8];
        int tap = blka / 3, cig = blka - tap * 3;
        goff[km] = cig * 9792 + ((tap / 3) * 34 + tap % 3) * 16;   // bytes
    }
    float gO[4], mO[4];
#pragma unroll
    for (int r = 0; r < 4; r++) {
        gO[r] = gb[(quad & 1) * 4 + r];
        mO[r] = mb[(quad & 1) * 4 + r];
    }
    float ls[4] = {0.f, 0.f, 0.f, 0.f}, ls2[4] = {0.f, 0.f, 0.f, 0.f};

    for (int g = wid; g < 32; g += 4) {
        int px = g * 16 + n;
        int rr = px >> 5, cc = px & 31;
        int off0 = CW4_OFF + (rr * 34 + cc) * 16;
        f32x4 acc = {0.f, 0.f, 0.f, 0.f};
#pragma unroll
        for (int km = 0; km < 7; km++)
            acc = __builtin_amdgcn_mfma_f32_16x16x32_bf16(
                gfr[km], *(const bfrag*)(LDS + off0 + goff[km]), acc, 0, 0, 0);
        int ra = r0 + rr, ca = c0 + cc;
        bool wr = !edge || (ra < HH && ca < WW);
#pragma unroll
        for (int reg = 0; reg < 4; reg++) {
            float val;
            if (quad < 2) val = acc[reg] + gO[reg];
            else          val = __builtin_amdgcn_rcpf(1.f + __expf(-(acc[reg] + mO[reg])));
            float other = __shfl_xor(val, 32);  // G <-> sig(M)
            if (quad < 2 && wr) {
                float y = val * other;
                int ch = quad * 4 + reg;
                out[(size_t)(b * 8 + ch) * HW + (size_t)ra * WW + ca] = y;
                ls[reg] += y;
                ls2[reg] += y * y;
            }
        }
    }
#pragma unroll
    for (int m = 1; m < 16; m <<= 1) {
#pragma unroll
        for (int r = 0; r < 4; r++) {
            ls[r] += __shfl_xor(ls[r], m);
            ls2[r] += __shfl_xor(ls2[r], m);
        }
    }
    if (n == 0 && quad < 2) {
        int hash = (blockIdx.x + GX * blockIdx.y + GX * GY * blockIdx.z) & 63;
#pragma unroll
        for (int r = 0; r < 4; r++) {
            atomicAdd(&stats[(quad * 4 + r) * 64 + hash], (double)ls[r]);
            atomicAdd(&stats[(8 + quad * 4 + r) * 64 + hash], (double)ls2[r]);
        }
    }
}

// ===========================================================================
// ============ fallback (tiny workspace) kernels ============================
// ===========================================================================
__global__ void k_pool5(const float* __restrict__ x, unsigned short* __restrict__ p5i) {
    int id = blockIdx.x * 256 + threadIdx.x;
    int bc = id / 3600, cell = id % 3600;
    int b = bc >> 3, c = bc & 7;
    int pi = cell / 60, pj = cell % 60;
    const float* rp = x + (size_t)bc * HW + pi * 5 * WW + pj * 5;
    float s = 0.f;
#pragma unroll
    for (int u = 0; u < 5; u++)
#pragma unroll
        for (int v = 0; v < 5; v++) s += rp[u * WW + v];
    p5i[((size_t)b * 3600 + cell) * 8 + c] = (unsigned short)f2bf(s * 0.04f);
}

__global__ void k_poolD(const unsigned short* __restrict__ p5i,
                        unsigned short* __restrict__ p10i,
                        unsigned short* __restrict__ p15i) {
    int id = blockIdx.x * 256 + threadIdx.x;
    if (id < 230400) {
        int bc = id / 900, cell = id % 900;
        int b = bc >> 3, c = bc & 7;
        int pi = cell / 30, pj = cell % 30;
        const unsigned short* base = p5i + ((size_t)b * 3600) * 8 + c;
        float s = bf2f(base[((2 * pi) * 60 + 2 * pj) * 8]) +
                  bf2f(base[((2 * pi) * 60 + 2 * pj + 1) * 8]) +
                  bf2f(base[((2 * pi + 1) * 60 + 2 * pj) * 8]) +
                  bf2f(base[((2 * pi + 1) * 60 + 2 * pj + 1) * 8]);
        p10i[((size_t)b * 900 + cell) * 8 + c] = (unsigned short)f2bf(s * 0.25f);
    } else if (id < 332800) {
        int id2 = id - 230400;
        int bc = id2 / 400, cell = id2 % 400;
        int b = bc >> 3, c = bc & 7;
        int pi = cell / 20, pj = cell % 20;
        const unsigned short* base = p5i + ((size_t)b * 3600) * 8 + c;
        float s = 0.f;
#pragma unroll
        for (int u = 0; u < 3; u++)
#pragma unroll
            for (int v = 0; v < 3; v++)
                s += bf2f(base[((3 * pi + u) * 60 + 3 * pj + v) * 8]);
        p15i[((size_t)b * 400 + cell) * 8 + c] = (unsigned short)f2bf(s * (1.f / 9.f));
    }
}

template <int K, int PW>
__device__ __forceinline__ void up_load(const unsigned short* __restrict__ pooled,
                                        int b, int r0, int c0, int t, uint4* v) {
#pragma unroll
    for (int it = 0; it < 3; it++) {
        int idx = t + 256 * it;
        uint4 val = {0u, 0u, 0u, 0u};
        if (idx < XPX) {
            int i = idx / 36, j = idx - i * 36;
            int ra = r0 - 2 + i, ca = c0 - 2 + j;
            if (ra >= 0 && ra < HH && ca >= 0 && ca < WW) {
                int pi = (int)((unsigned)ra / K);
                int pj = (int)((unsigned)ca / K);
                val = *(const uint4*)&pooled[((size_t)b * (PW * PW) + pi * PW + pj) * 8];
            }
        }
        v[it] = val;
    }
}

__device__ __forceinline__ void up_store(short* xuU, int t, const uint4* v) {
#pragma unroll
    for (int it = 0; it < 3; it++) {
        int idx = t + 256 * it;
        if (idx < XPX) *(uint4*)&xuU[idx * 8] = v[it];
    }
}

__device__ __forceinline__ void c_phase(const short* xuX, const short* xuU,
                                        short* cwP,
                                        const unsigned short* __restrict__ cBs,
                                        const float* __restrict__ bias,
                                        int r0, int c0, int lane, int wid, bool edge) {
    const int n = lane & 15, quad = lane >> 4;
    const int qh = quad >> 1, ql = quad & 1;
    const short* xbase = ql ? xuU : xuX;
    bfrag wfr[5];
    int dpoff[5];
#pragma unroll
    for (int km = 0; km < 5; km++) {
        int tapw = km * 2 + qh;
        int tapa = (tapw > 8) ? 8 : tapw;
        wfr[km] = *(const bfrag*)&cBs[(n * 10 + tapw) * 16 + ql * 8];
        dpoff[km] = ((tapa / 3) * 36 + tapa % 3) * 8;
    }
    float bO[4];
#pragma unroll
    for (int r = 0; r < 4; r++) bO[r] = bias[(quad & 1) * 4 + r];

    for (int g = wid; g < 39; g += 4) {
        int px = g * 16 + n;
        if (px > 611) px = 611;
        int rp = (int)((unsigned)px / 34u);
        int cp = px - rp * 34;
        int pb = (rp * 36 + cp) * 8;
        f32x4 acc = {0.f, 0.f, 0.f, 0.f};
#pragma unroll
        for (int km = 0; km < 5; km++)
            acc = __builtin_amdgcn_mfma_f32_16x16x32_bf16(
                wfr[km], *(const bfrag*)&xbase[pb + dpoff[km]], acc, 0, 0, 0);
        if (quad < 2) {
            bf16x4 pk;
#pragma unroll
            for (int r = 0; r < 4; r++) pk[r] = (__bf16)(acc[r] + bO[r]);
            if (edge) {
                int ra = r0 - 1 + rp, ca = c0 - 1 + cp;
                if (ra < 0 || ra >= HH || ca < 0 || ca >= WW) {
#pragma unroll
                    for (int r = 0; r < 4; r++) pk[r] = (__bf16)0.f;
                }
            }
            *(bf16x4*)&cwP[px * 8 + quad * 4] = pk;
        }
    }
}

__global__ __launch_bounds__(256, 3) void k_fused_fb(
    const float* __restrict__ x,
    const unsigned short* __restrict__ p5i, const unsigned short* __restrict__ p10i,
    const unsigned short* __restrict__ p15i,
    const unsigned short* __restrict__ cBg, const unsigned short* __restrict__ gBg,
    const float* __restrict__ b5, const float* __restrict__ b10, const float* __restrict__ b15,
    const float* __restrict__ gb, const float* __restrict__ mb,
    float* __restrict__ out, double* __restrict__ stats) {
    __shared__ __align__(16) short xuX[XPX * 8];
    __shared__ __align__(16) short xuU[XPX * 8];
    __shared__ __align__(16) short cwS[3 * CWSTRIDE];

    const int b = blockIdx.z;
    const int r0 = blockIdx.y * 16, c0 = blockIdx.x * 32;
    const int t = threadIdx.x, lane = t & 63, wid = t >> 6;
    const bool edge = (blockIdx.x == 0) | (blockIdx.x == GX - 1) |
                      (blockIdx.y == 0) | (blockIdx.y == GY - 1);

    uint4 upv[3];
    up_load<5, 60>(p5i, b, r0, c0, t, upv);

    for (int idx = t; idx < 1440; idx += 256) {
        int cp = idx / 360, rem = idx % 360;
        int i = rem / 18, jp = rem % 18;
        int j = 2 * jp;
        int ra = r0 - 2 + i, ca = c0 - 2 + j;
        float2 v0 = {0.f, 0.f}, v1 = {0.f, 0.f};
        if (ra >= 0 && ra < HH && ca >= 0 && ca <= WW - 2) {
            size_t base = ((size_t)(b * 8 + 2 * cp) * HH + ra) * WW + ca;
            v0 = *(const float2*)&x[base];
            v1 = *(const float2*)&x[base + HW];
        }
        unsigned pA = (unsigned short)f2bf(v0.x) | ((unsigned)(unsigned short)f2bf(v1.x) << 16);
        unsigned pB = (unsigned short)f2bf(v0.y) | ((unsigned)(unsigned short)f2bf(v1.y) << 16);
        int px = i * 36 + j;
        *(unsigned*)&xuX[px * 8 + 2 * cp] = pA;
        *(unsigned*)&xuX[(px + 1) * 8 + 2 * cp] = pB;
    }
    up_store(xuU, t, upv);
    __syncthreads();

    c_phase(xuX, xuU, cwS, cBg, b5, r0, c0, lane, wid, edge);
    up_load<10, 30>(p10i, b, r0, c0, t, upv);
    __syncthreads();
    up_store(xuU, t, upv);
    __syncthreads();

    c_phase(xuX, xuU, cwS + CWSTRIDE, cBg + 2560, b10, r0, c0, lane, wid, edge);
    up_load<15, 20>(p15i, b, r0, c0, t, upv);
    __syncthreads();
    up_store(xuU, t, upv);
    __syncthreads();

    c_phase(xuX, xuU, cwS + 2 * CWSTRIDE, cBg + 5120, b15, r0, c0, lane, wid, edge);
    __syncthreads();

    const int n = lane & 15, quad = lane >> 4;
    bfrag gfr[7];
    int goff[7];
#pragma unroll
    for (int km = 0; km < 7; km++) {
        int blkw = km * 4 + quad;
        int blka = (blkw > 26) ? 26 : blkw;
        gfr[km] = *(const bfrag*)&gBg[(n * 28 + blkw) * 8];
        int tap = blka / 3, cig = blka - tap * 3;
        goff[km] = cig * CWSTRIDE + ((tap / 3) * 34 + tap % 3) * 8;
    }
    float gO[4], mO[4];
#pragma unroll
    for (int r = 0; r < 4; r++) {
        gO[r] = gb[(quad & 1) * 4 + r];
        mO[r] = mb[(quad & 1) * 4 + r];
    }
    float ls[4] = {0.f, 0.f, 0.f, 0.f}, ls2[4] = {0.f, 0.f, 0.f, 0.f};

    for (int g = wid; g < 32; g += 4) {
        int px = g * 16 + n;
        int rr = px >> 5, cc = px & 31;
        int off0 = (rr * 34 + cc) * 8;
        f32x4 acc = {0.f, 0.f, 0.f, 0.f};
#pragma unroll
        for (int km = 0; km < 7; km++)
            acc = __builtin_amdgcn_mfma_f32_16x16x32_bf16(
                gfr[km], *(const bfrag*)&cwS[off0 + goff[km]], acc, 0, 0, 0);
        int ra = r0 + rr, ca = c0 + cc;
        bool wr = !edge || (ra < HH && ca < WW);
#pragma unroll
        for (int reg = 0; reg < 4; reg++) {
            float val;
            if (quad < 2) val = acc[reg] + gO[reg];
            else          val = __builtin_amdgcn_rcpf(1.f + __expf(-(acc[reg] + mO[reg])));
            float other = __shfl_xor(val, 32);
            if (quad < 2 && wr) {
                float y = val * other;
                int ch = quad * 4 + reg;
                out[(size_t)(b * 8 + ch) * HW + (size_t)ra * WW + ca] = y;
                ls[reg] += y;
                ls2[reg] += y * y;
            }
        }
    }
#pragma unroll
    for (int m = 1; m < 16; m <<= 1) {
#pragma unroll
        for (int r = 0; r < 4; r++) {
            ls[r] += __shfl_xor(ls[r], m);
            ls2[r] += __shfl_xor(ls2[r], m);
        }
    }
    if (n == 0 && quad < 2) {
        int hash = (blockIdx.x + GX * blockIdx.y + GX * GY * blockIdx.z) & 63;
#pragma unroll
        for (int r = 0; r < 4; r++) {
            atomicAdd(&stats[(quad * 4 + r) * 64 + hash], (double)ls[r]);
            atomicAdd(&stats[(8 + quad * 4 + r) * 64 + hash], (double)ls2[r]);
        }
    }
}

// ---------------------------------------------------------------------------
__global__ void k_stats(const double* __restrict__ stats, const float* __restrict__ gamma,
                        const float* __restrict__ beta, float* __restrict__ ss) {
    __shared__ double red[16][16];
    int t = threadIdx.x;
    int row = t >> 4, col = t & 15;
    double s = stats[row * 64 + col] + stats[row * 64 + col + 16] +
               stats[row * 64 + col + 32] + stats[row * 64 + col + 48];
    red[row][col] = s;
    __syncthreads();
    if (t < 16) {
        double tot = 0.0;
#pragma unroll
        for (int i = 0; i < 16; i++) tot += red[t][i];
        red[t][0] = tot;
    }
    __syncthreads();
    if (t < 8) {
        double N = (double)NPX;
        double mean = red[t][0] / N;
        double var = red[8 + t][0] / N - mean * mean;
        double scale = (double)gamma[t] / sqrt(var + 1e-5);
        ss[t] = (float)scale;
        ss[8 + t] = (float)((double)beta[t] - mean * scale);
    }
}

__global__ void k_norm(float* __restrict__ out, const float* __restrict__ ss) {
    int i = blockIdx.x * 256 + threadIdx.x;
    if (i < (BN * 8 * HW) / 4) {
        int plane = (i * 4) / HW;
        int ch = plane & 7;
        float sc = ss[ch], sh = ss[8 + ch];
        float4* p = (float4*)out + i;
        float4 v = *p;
        v.x = v.x * sc + sh;
        v.y = v.y * sc + sh;
        v.z = v.z * sc + sh;
        v.w = v.w * sc + sh;
        *p = v;
    }
}

// ---------------------------------------------------------------------------
extern "C" void kernel_launch(void* const* d_in, const int* in_sizes, int n_in,
                              void* d_out, int out_size, void* d_ws, size_t ws_size,
                              hipStream_t stream) {
    const float* x = (const float*)d_in[0];
    const float* w5 = (const float*)d_in[1];
    const float* b5 = (const float*)d_in[2];
    const float* w10 = (const float*)d_in[3];
    const float* b10 = (const float*)d_in[4];
    const float* w15 = (const float*)d_in[5];
    const float* b15 = (const float*)d_in[6];
    const float* gw = (const float*)d_in[7];
    const float* gb = (const float*)d_in[8];
    const float* mw = (const float*)d_in[9];
    const float* mb = (const float*)d_in[10];
    const float* gamma = (const float*)d_in[11];
    const float* beta = (const float*)d_in[12];
    float* out = (float*)d_out;

    unsigned short* p5i = (unsigned short*)((char*)d_ws + P5I_BYTE_OFF);
    unsigned short* p10i = (unsigned short*)((char*)d_ws + P10I_BYTE_OFF);
    unsigned short* p15i = (unsigned short*)((char*)d_ws + P15I_BYTE_OFF);
    short* cBg = (short*)((char*)d_ws + CWB_BYTE_OFF);
    short* gBg = (short*)((char*)d_ws + GWB_BYTE_OFF);
    double* stats = (double*)((char*)d_ws + STAT_BYTE_OFF);
    float* ss = (float*)((char*)d_ws + SS_BYTE_OFF);
    unsigned short* xbf = (unsigned short*)((char*)d_ws + XBF_BYTE_OFF);

    dim3 grid(GX, GY, BN);
    if (ws_size >= XBF_END) {
        k_xbf<<<dim3(352, 32), 256, 0, stream>>>(x, xbf, w5, w10, w15, gw, mw,
                                                 cBg, gBg, stats);
        k_poolAll<<<dim3(100, 32), 256, 0, stream>>>(xbf, p5i, p10i, p15i);
        k_fused4<<<grid, 256, 0, stream>>>(xbf, p5i, p10i, p15i,
                                           (const unsigned short*)cBg, (const unsigned short*)gBg,
                                           b5, b10, b15, gb, mb, out, stats);
    } else {
        k_setup<<<1, 256, 0, stream>>>(w5, w10, w15, gw, mw, cBg, gBg, stats);
        k_pool5<<<3600, 256, 0, stream>>>(x, p5i);
        k_poolD<<<1300, 256, 0, stream>>>(p5i, p10i, p15i);
        k_fused_fb<<<grid, 256, 0, stream>>>(x, p5i, p10i, p15i,
                                             (const unsigned short*)cBg, (const unsigned short*)gBg,
                                             b5, b10, b15, gb, mb, out, stats);
    }
    k_stats<<<1, 256, 0, stream>>>(stats, gamma, beta, ss);
    k_norm<<<(BN * 8 * HW / 4 + 255) / 256, 256, 0, stream>>>(out, ss);
}